// Round 4
// baseline (360.773 us; speedup 1.0000x reference)
//
#include <hip/hip_runtime.h>
#include <hip/hip_bf16.h>

// LSTM: S=128, N=2048, H=128, O=128. fp32 buffers, bf16 MFMA internally.
// 128 persistent blocks x 512 threads; block b owns samples [16b,16b+16).
// TRANSPOSED MFMA: D[j][sample] (weights as A-operand, data as B-operand) so each
// lane owns 4 consecutive gate/output dims for one sample:
//   - h feedback   -> one aligned ds_write_b64 (2-way bank access, free)
//   - pred store   -> one coalesced global_store_dwordx4
// Raw `s_waitcnt lgkmcnt(0); s_barrier` (m139 idiom) instead of __syncthreads:
// global stores / x prefetch loads are NOT drained at the barrier, removing the
// per-step vmcnt(0) stall. xg = x_t W_ih^T stays pipelined one step ahead.

#define S_LEN   128
#define N_BATCH 2048
#define H_DIM   128
#define O_DIM   128

using short8  = __attribute__((ext_vector_type(8))) short;  // 8 bf16 (4 VGPRs)
using short4v = __attribute__((ext_vector_type(4))) short;  // 4 bf16
using floatx4 = __attribute__((ext_vector_type(4))) float;  // 4 fp32 acc
typedef unsigned short u16;

#define ROWP     264                 // LDS row pitch in bf16 elems (256 + 8 pad)
#define BUFELEMS (16 * ROWP)         // one tile buffer: 16 rows x [x(0:128)|h(128:256)]

// LDS-only barrier: ds ops complete (lgkmcnt) but vmem (stores, prefetch) floats across.
#define BAR() asm volatile("s_waitcnt lgkmcnt(0)\n\ts_barrier" ::: "memory")

__device__ __forceinline__ u16 f2b(float f) {   // RNE f32->bf16
    unsigned int u = __float_as_uint(f);
    return (u16)((u + 0x7FFF + ((u >> 16) & 1)) >> 16);
}
__device__ __forceinline__ short8 pack8(const float* p) {
    short8 r;
#pragma unroll
    for (int i = 0; i < 8; ++i) r[i] = (short)f2b(p[i]);
    return r;
}
__device__ __forceinline__ short4v pack4(float4 f) {
    short4v r;
    r[0] = (short)f2b(f.x); r[1] = (short)f2b(f.y);
    r[2] = (short)f2b(f.z); r[3] = (short)f2b(f.w);
    return r;
}
__device__ __forceinline__ float sigmoidf_fast(float v) {
    return __builtin_amdgcn_rcpf(1.0f + __builtin_amdgcn_exp2f(-1.4426950408889634f * v));
}
__device__ __forceinline__ float tanhf_fast(float v) {
    return 1.0f - 2.0f * __builtin_amdgcn_rcpf(1.0f + __builtin_amdgcn_exp2f(2.8853900817779268f * v));
}

__global__ __launch_bounds__(512, 2)
void lstm_persist(const float* __restrict__ x,
                  const float* __restrict__ W_ih,
                  const float* __restrict__ W_hh,
                  const float* __restrict__ b_ih,
                  const float* __restrict__ b_hh,
                  const float* __restrict__ W_out,
                  const float* __restrict__ b_out,
                  float* __restrict__ pred) {
    __shared__ short sh[2 * BUFELEMS];

    const int tid  = (int)threadIdx.x;
    const int wave = tid >> 6;           // 0..7
    const int lane = tid & 63;
    const int quad = lane >> 4;          // 0..3
    const int l15  = lane & 15;
    const int n0   = (int)blockIdx.x * 16;
    const int jrow = wave * 16 + quad * 4;   // this lane's 4 consecutive j-dims

    // ---- weights into bf16 register fragments ----
    // Used as A-operand: A[m=l15 (j within tile)][k=quad*8+i]. Same per-lane data
    // as a B-frag, so loads are identical to before.
    short8 wx[4][4], wh[4][4], wo[4];
    floatx4 biasv[4];
#pragma unroll
    for (int t = 0; t < 4; ++t) {
        const int g = t * 128 + wave * 16 + l15;
#pragma unroll
        for (int kk = 0; kk < 4; ++kk) {
            wx[t][kk] = pack8(W_ih + g * H_DIM + kk * 32 + quad * 8);
            wh[t][kk] = pack8(W_hh + g * H_DIM + kk * 32 + quad * 8);
        }
        float4 bi = *reinterpret_cast<const float4*>(b_ih + t * 128 + jrow);
        float4 bh = *reinterpret_cast<const float4*>(b_hh + t * 128 + jrow);
        biasv[t] = floatx4{bi.x + bh.x, bi.y + bh.y, bi.z + bh.z, bi.w + bh.w};
    }
#pragma unroll
    for (int kk = 0; kk < 4; ++kk)
        wo[kk] = pack8(W_out + (wave * 16 + l15) * H_DIM + kk * 32 + quad * 8);
    float4 bo4 = *reinterpret_cast<const float4*>(b_out + jrow);

    // x loader: all 512 threads, one float4 each (16 rows x 128 cols)
    const int xm = tid >> 5;             // row 0..15
    const int xq = (tid & 31) * 4;       // col 0..124 step 4

    // ---- prologue: zero h(buf0) = h_{-1}; stage x_0->buf1, x_1->buf0 ----
    for (int i = tid; i < 16 * 128; i += 512)
        sh[(i >> 7) * ROWP + 128 + (i & 127)] = 0;
    {
        float4 f0 = *reinterpret_cast<const float4*>(x + ((size_t)(n0 + xm)) * H_DIM + xq);
        float4 f1 = *reinterpret_cast<const float4*>(x + ((size_t)N_BATCH + n0 + xm) * H_DIM + xq);
        *reinterpret_cast<short4v*>(&sh[BUFELEMS + xm * ROWP + xq]) = pack4(f0);
        *reinterpret_cast<short4v*>(&sh[xm * ROWP + xq]) = pack4(f1);
    }
    float4 xcur  = *reinterpret_cast<const float4*>(x + ((size_t)2 * N_BATCH + n0 + xm) * H_DIM + xq);
    float4 xnext = *reinterpret_cast<const float4*>(x + ((size_t)3 * N_BATCH + n0 + xm) * H_DIM + xq);
    BAR();

    const int arow = l15 * ROWP + quad * 8;   // data-frag base: row l15 (sample), k=quad*8+..

    // xg_0 from buf1 x-region (transposed: D[j][m])
    floatx4 xg0 = biasv[0], xg1 = biasv[1], xg2 = biasv[2], xg3 = biasv[3];
#pragma unroll
    for (int kk = 0; kk < 4; ++kk) {
        short8 ax = *reinterpret_cast<const short8*>(&sh[BUFELEMS + arow + kk * 32]);
        xg0 = __builtin_amdgcn_mfma_f32_16x16x32_bf16(wx[0][kk], ax, xg0, 0, 0, 0);
        xg1 = __builtin_amdgcn_mfma_f32_16x16x32_bf16(wx[1][kk], ax, xg1, 0, 0, 0);
        xg2 = __builtin_amdgcn_mfma_f32_16x16x32_bf16(wx[2][kk], ax, xg2, 0, 0, 0);
        xg3 = __builtin_amdgcn_mfma_f32_16x16x32_bf16(wx[3][kk], ax, xg3, 0, 0, 0);
    }
    BAR();   // buf1-x reads done before step 0 stages x_2 there

    float cc[4] = {0.f, 0.f, 0.f, 0.f};  // cell: c[j=jrow+r][sample l15]

    // ---- main recurrence. Buffer B_s = buf[s&1] holds [x_{s+1} | h_{s-1}]. ----
    for (int s = 0; s < S_LEN; ++s) {
        short* shb = sh + (s & 1) * BUFELEMS;
        short* shn = sh + ((s & 1) ^ 1) * BUFELEMS;

        // ---- critical path: h_{s-1} gates (K=128), split-K depth-2 chains ----
        short8 ah0 = *reinterpret_cast<const short8*>(&shb[arow + 128 + 0 * 32]);
        short8 ah1 = *reinterpret_cast<const short8*>(&shb[arow + 128 + 1 * 32]);
        short8 ah2 = *reinterpret_cast<const short8*>(&shb[arow + 128 + 2 * 32]);
        short8 ah3 = *reinterpret_cast<const short8*>(&shb[arow + 128 + 3 * 32]);

        floatx4 g0a = xg0, g1a = xg1, g2a = xg2, g3a = xg3;   // seeded by pipelined xg_s
        floatx4 g0b = {0,0,0,0}, g1b = {0,0,0,0}, g2b = {0,0,0,0}, g3b = {0,0,0,0};
        floatx4 ao = {bo4.x, bo4.y, bo4.z, bo4.w};            // out-proj of h_{s-1}

        g0a = __builtin_amdgcn_mfma_f32_16x16x32_bf16(wh[0][0], ah0, g0a, 0, 0, 0);
        g1a = __builtin_amdgcn_mfma_f32_16x16x32_bf16(wh[1][0], ah0, g1a, 0, 0, 0);
        g2a = __builtin_amdgcn_mfma_f32_16x16x32_bf16(wh[2][0], ah0, g2a, 0, 0, 0);
        g3a = __builtin_amdgcn_mfma_f32_16x16x32_bf16(wh[3][0], ah0, g3a, 0, 0, 0);
        g0b = __builtin_amdgcn_mfma_f32_16x16x32_bf16(wh[0][1], ah1, g0b, 0, 0, 0);
        g1b = __builtin_amdgcn_mfma_f32_16x16x32_bf16(wh[1][1], ah1, g1b, 0, 0, 0);
        g2b = __builtin_amdgcn_mfma_f32_16x16x32_bf16(wh[2][1], ah1, g2b, 0, 0, 0);
        g3b = __builtin_amdgcn_mfma_f32_16x16x32_bf16(wh[3][1], ah1, g3b, 0, 0, 0);
        ao  = __builtin_amdgcn_mfma_f32_16x16x32_bf16(wo[0],    ah0, ao,  0, 0, 0);
        g0a = __builtin_amdgcn_mfma_f32_16x16x32_bf16(wh[0][2], ah2, g0a, 0, 0, 0);
        g1a = __builtin_amdgcn_mfma_f32_16x16x32_bf16(wh[1][2], ah2, g1a, 0, 0, 0);
        g2a = __builtin_amdgcn_mfma_f32_16x16x32_bf16(wh[2][2], ah2, g2a, 0, 0, 0);
        g3a = __builtin_amdgcn_mfma_f32_16x16x32_bf16(wh[3][2], ah2, g3a, 0, 0, 0);
        ao  = __builtin_amdgcn_mfma_f32_16x16x32_bf16(wo[1],    ah1, ao,  0, 0, 0);
        g0b = __builtin_amdgcn_mfma_f32_16x16x32_bf16(wh[0][3], ah3, g0b, 0, 0, 0);
        g1b = __builtin_amdgcn_mfma_f32_16x16x32_bf16(wh[1][3], ah3, g1b, 0, 0, 0);
        g2b = __builtin_amdgcn_mfma_f32_16x16x32_bf16(wh[2][3], ah3, g2b, 0, 0, 0);
        g3b = __builtin_amdgcn_mfma_f32_16x16x32_bf16(wh[3][3], ah3, g3b, 0, 0, 0);
        ao  = __builtin_amdgcn_mfma_f32_16x16x32_bf16(wo[2],    ah2, ao,  0, 0, 0);
        ao  = __builtin_amdgcn_mfma_f32_16x16x32_bf16(wo[3],    ah3, ao,  0, 0, 0);

        // ---- off-path: xg_{s+1} from x-region of B_s ----
        xg0 = biasv[0]; xg1 = biasv[1]; xg2 = biasv[2]; xg3 = biasv[3];
#pragma unroll
        for (int kk = 0; kk < 4; ++kk) {
            short8 ax = *reinterpret_cast<const short8*>(&shb[arow + kk * 32]);
            xg0 = __builtin_amdgcn_mfma_f32_16x16x32_bf16(wx[0][kk], ax, xg0, 0, 0, 0);
            xg1 = __builtin_amdgcn_mfma_f32_16x16x32_bf16(wx[1][kk], ax, xg1, 0, 0, 0);
            xg2 = __builtin_amdgcn_mfma_f32_16x16x32_bf16(wx[2][kk], ax, xg2, 0, 0, 0);
            xg3 = __builtin_amdgcn_mfma_f32_16x16x32_bf16(wx[3][kk], ax, xg3, 0, 0, 0);
        }

        // pred_{s-1}: one coalesced dwordx4 per lane (no barrier drain now)
        if (s > 0) {
            float4 po = {ao[0], ao[1], ao[2], ao[3]};
            *reinterpret_cast<float4*>(
                pred + ((size_t)(s - 1) * N_BATCH + n0 + l15) * O_DIM + jrow) = po;
        }

        // stage x_{s+2} into B_{s+1}; refill xnext with x_{s+3}
        if (s <= 125)
            *reinterpret_cast<short4v*>(&shn[xm * ROWP + xq]) = pack4(xcur);
        if (s <= 124)
            xnext = *reinterpret_cast<const float4*>(
                x + ((size_t)(s + 3) * N_BATCH + n0 + xm) * H_DIM + xq);

        // ---- activations + state update (lane owns j=jrow..jrow+3, sample l15) ----
        short4v hp;
#pragma unroll
        for (int r = 0; r < 4; ++r) {
            float iv = sigmoidf_fast(g0a[r] + g0b[r]);
            float fv = sigmoidf_fast(g1a[r] + g1b[r]);
            float gv = tanhf_fast(g2a[r] + g2b[r]);
            float ov = sigmoidf_fast(g3a[r] + g3b[r]);
            cc[r] = fv * cc[r] + iv * gv;
            hp[r] = (short)f2b(ov * tanhf_fast(cc[r]));
        }
        // one aligned ds_write_b64: row=sample l15, cols jrow..jrow+3
        *reinterpret_cast<short4v*>(&shn[l15 * ROWP + 128 + jrow]) = hp;

        xcur = xnext;
        BAR();
    }

    // ---- epilogue: pred_{S-1} from h_127 in B_128 = buf0 ----
    floatx4 ao = {bo4.x, bo4.y, bo4.z, bo4.w};
#pragma unroll
    for (int kk = 0; kk < 4; ++kk) {
        short8 ah = *reinterpret_cast<const short8*>(&sh[arow + 128 + kk * 32]);
        ao = __builtin_amdgcn_mfma_f32_16x16x32_bf16(wo[kk], ah, ao, 0, 0, 0);
    }
    float4 po = {ao[0], ao[1], ao[2], ao[3]};
    *reinterpret_cast<float4*>(
        pred + ((size_t)(S_LEN - 1) * N_BATCH + n0 + l15) * O_DIM + jrow) = po;
}

extern "C" void kernel_launch(void* const* d_in, const int* in_sizes, int n_in,
                              void* d_out, int out_size, void* d_ws, size_t ws_size,
                              hipStream_t stream) {
    const float* x    = (const float*)d_in[0];
    const float* Wih  = (const float*)d_in[1];
    const float* Whh  = (const float*)d_in[2];
    const float* bih  = (const float*)d_in[3];
    const float* bhh  = (const float*)d_in[4];
    const float* Wout = (const float*)d_in[5];
    const float* bout = (const float*)d_in[6];
    float* pred = (float*)d_out;

    lstm_persist<<<dim3(N_BATCH / 16), dim3(512), 0, stream>>>(
        x, Wih, Whh, bih, bhh, Wout, bout, pred);
}